// Round 8
// baseline (215.609 us; speedup 1.0000x reference)
//
#include <hip/hip_runtime.h>

typedef __attribute__((ext_vector_type(8))) short bf16x8;
typedef __attribute__((ext_vector_type(4))) float f32x4;

constexpr int kB = 2, kN = 4096, kC = 512, kNH = 8, kHD = 64;
constexpr int kBN = kB * kN;                 // 8192
constexpr int kWElems = 262144;              // 512*512
constexpr int kWAll = 6 * kWElems;           // 6 weight matrices
constexpr int kWExtra = 3584;                // dwk(1536) + dwb(512) + dwkT(1536)
constexpr float kQScale = 0.1803368801f;     // (1/8) * log2(e)

__device__ __forceinline__ short f2bf(float f) {
  union { float f; unsigned u; } v; v.f = f;
  unsigned r = v.u + 0x7fffu + ((v.u >> 16) & 1u);
  return (short)(r >> 16);
}
__device__ __forceinline__ float bf2f(short s) {
  union { unsigned u; float f; } v; v.u = ((unsigned)(unsigned short)s) << 16;
  return v.f;
}
__device__ __forceinline__ float exp2_(float x) {
#if __has_builtin(__builtin_amdgcn_exp2f)
  return __builtin_amdgcn_exp2f(x);
#else
  return exp2f(x);
#endif
}
// pack two f32 -> two bf16 (round-half-up) in one dword via v_perm
__device__ __forceinline__ unsigned pk2bf(float a, float b) {
  union { float f; unsigned u; } ua, ub; ua.f = a; ub.f = b;
#if __has_builtin(__builtin_amdgcn_perm)
  return __builtin_amdgcn_perm(ub.u + 0x8000u, ua.u + 0x8000u, 0x07060302u);
#else
  return ((ua.u + 0x8000u) >> 16) | (((ub.u + 0x8000u) >> 16) << 16);
#endif
}

__device__ __forceinline__ bf16x8 ld8(const short* p) { return *(const bf16x8*)p; }
__device__ __forceinline__ bf16x8 ld8(const float* p) {
  float4 a = *(const float4*)p;
  float4 b = *(const float4*)(p + 4);
  bf16x8 r;
  r[0] = f2bf(a.x); r[1] = f2bf(a.y); r[2] = f2bf(a.z); r[3] = f2bf(a.w);
  r[4] = f2bf(b.x); r[5] = f2bf(b.y); r[6] = f2bf(b.z); r[7] = f2bf(b.w);
  return r;
}

// async 16B global->LDS (LDS dest wave-uniform base + 16*lane).
__device__ __forceinline__ void gload_lds16(const void* g, void* l) {
  __builtin_amdgcn_global_load_lds(
      (const __attribute__((address_space(1))) void*)g,
      (__attribute__((address_space(3))) void*)l, 16, 0, 0);
}

// K0: classify input dtype on-device.
__global__ void detect_dtype(const unsigned* __restrict__ x, int* __restrict__ flag) {
  const int lane = threadIdx.x & 63;
  unsigned w = x[lane];
  int e = (int)((w >> 7) & 0xffu);
  bool bf = (e >= 100 && e <= 140);
  unsigned long long m = __ballot(bf);
  if (lane == 0) *flag = (__popcll(m) >= 32) ? 1 : 0;
}

// K0b: weights AND x -> bf16 in one launch.
// dst layout: [Wq,Wk,Wv,Wc,Wa,Wco | dwk 1536 | dwb 512 | dwkT 3x512]; xb separate.
constexpr int kW8 = kWAll / 8;        // 196608
constexpr int kX8 = kBN * kC / 8;     // 524288
__global__ __launch_bounds__(256) void convert_all(
    const void* Wq, const void* Wk, const void* Wv, const void* Wc,
    const void* Wa, const void* Wco, const void* dwk, const void* dwb,
    const void* x, const int* __restrict__ flag, short* __restrict__ dst,
    short* __restrict__ xb) {
  const int gtid = blockIdx.x * 256 + threadIdx.x;
  const bool bf = (*flag != 0);
  if (gtid < kW8) {
    const int e = gtid * 8;
    const int t = e >> 18, off = e & (kWElems - 1);
    const void* src = (t == 0) ? Wq : (t == 1) ? Wk : (t == 2) ? Wv
                    : (t == 3) ? Wc : (t == 4) ? Wa : Wco;
    bf16x8 v = bf ? ld8((const short*)src + off) : ld8((const float*)src + off);
    *(bf16x8*)(dst + e) = v;
  } else if (gtid < kW8 + kWExtra) {
    const int eoff = gtid - kW8;
    if (eoff < 1536) {
      dst[kWAll + eoff] = bf ? ((const short*)dwk)[eoff]
                             : f2bf(((const float*)dwk)[eoff]);
    } else if (eoff < 2048) {
      const int i = eoff - 1536;
      dst[kWAll + 1536 + i] = bf ? ((const short*)dwb)[i]
                                 : f2bf(((const float*)dwb)[i]);
    } else {
      const int t2 = eoff - 2048;
      const int tap = t2 >> 9, c = t2 & 511;
      dst[kWAll + 2048 + t2] = bf ? ((const short*)dwk)[c * 3 + tap]
                                  : f2bf(((const float*)dwk)[c * 3 + tap]);
    }
  } else if (gtid < kW8 + kWExtra + kX8) {
    const int e = (gtid - kW8 - kWExtra) * 8;
    bf16x8 v = bf ? ld8((const short*)x + e) : ld8((const float*)x + e);
    *(bf16x8*)(xb + e) = v;
  }
}

// ---------------------------------------------------------------------------
// K1: fused input projection GEMM [8192x512] x [2048x512]^T.
// BK=64, XOR-source-swizzled staging. LDS-bounce epilogue. NEW: XCD-aware
// bijective blockIdx swizzle (nwg=1024, %8==0): blocks resident on one XCD
// share 8 A-panels (1MB) + all B panels (2MB) -> L2-resident re-reads.
// ---------------------------------------------------------------------------
__global__ __launch_bounds__(256, 3) void proj_gemm(
    const short* __restrict__ xb, const short* __restrict__ wb,
    short* __restrict__ q, short* __restrict__ k, short* __restrict__ vT,
    short* __restrict__ ci) {
  __shared__ __align__(16) short Sh[16384];     // 32 KB: As | Bs, reused by epilogue
  short* As = Sh;                               // 128*64
  short* Bs = Sh + 8192;                        // 128*64
  const int t = threadIdx.x;
  const int wave = t >> 6, lane = t & 63;
  const int row = lane & 15, quad = lane >> 4;
  const int swz = (blockIdx.x & 7) * 128 + (blockIdx.x >> 3);   // XCD swizzle
  const int bn = swz & 15;
  const int bm = swz >> 4;
  const int m0 = bm * 128, n0 = bn * 128;
  const int wm = wave & 1, wn = wave >> 1;
  const int lrow = lane >> 3, lch = lane & 7;   // staging: 8 rows x 8 chunks

  f32x4 acc[4][4];
#pragma unroll
  for (int mi = 0; mi < 4; ++mi)
#pragma unroll
    for (int ni = 0; ni < 4; ++ni)
#pragma unroll
      for (int r = 0; r < 4; ++r) acc[mi][ni][r] = 0.0f;

  for (int k0 = 0; k0 < kC; k0 += 64) {
#pragma unroll
    for (int p = 0; p < 4; ++p) {
      const int m = wave * 32 + p * 8 + lrow;     // tile row this lane stages
      const int kch = lch ^ (m & 7);              // swizzled source chunk
      gload_lds16(xb + (size_t)(m0 + m) * kC + k0 + kch * 8,
                  &As[(wave * 32 + p * 8) * 64]);
      gload_lds16(wb + (size_t)(n0 + m) * kC + k0 + kch * 8,
                  &Bs[(wave * 32 + p * 8) * 64]);
    }
    __syncthreads();

#pragma unroll
    for (int kk2 = 0; kk2 < 2; ++kk2) {
      bf16x8 af[4], bfr[4];
#pragma unroll
      for (int mi = 0; mi < 4; ++mi) {
        const int m = wm * 64 + mi * 16 + row;
        const int ch = (kk2 * 4 + quad) ^ (m & 7);
        af[mi] = *(const bf16x8*)(&As[m * 64 + ch * 8]);
      }
#pragma unroll
      for (int ni = 0; ni < 4; ++ni) {
        const int n = wn * 64 + ni * 16 + row;
        const int ch = (kk2 * 4 + quad) ^ (n & 7);
        bfr[ni] = *(const bf16x8*)(&Bs[n * 64 + ch * 8]);
      }
#pragma unroll
      for (int mi = 0; mi < 4; ++mi)
#pragma unroll
        for (int ni = 0; ni < 4; ++ni)
          acc[mi][ni] = __builtin_amdgcn_mfma_f32_16x16x32_bf16(
              af[mi], bfr[ni], acc[mi][ni], 0, 0, 0);
    }
    __syncthreads();
  }

  // ---- epilogue: LDS bounce -> coalesced stores ----
  const int mat = n0 >> 9;
  const float scale = (mat == 0) ? kQScale : 1.0f;
  if (mat != 2) {
#pragma unroll
    for (int mi = 0; mi < 4; ++mi)
#pragma unroll
      for (int ni = 0; ni < 4; ++ni)
#pragma unroll
        for (int r = 0; r < 4; ++r) {
          const int m = wm * 64 + mi * 16 + quad * 4 + r;
          const int n = wn * 64 + ni * 16 + row;
          Sh[m * 128 + (((n >> 3) ^ (m & 15)) * 8) + (n & 7)] =
              f2bf(acc[mi][ni][r] * scale);
        }
  } else {
#pragma unroll
    for (int mi = 0; mi < 4; ++mi)
#pragma unroll
      for (int ni = 0; ni < 4; ++ni)
#pragma unroll
        for (int r = 0; r < 4; ++r) {
          const int m = wm * 64 + mi * 16 + quad * 4 + r;
          const int n = wn * 64 + ni * 16 + row;
          Sh[n * 128 + (((m >> 3) ^ (n & 15)) * 8) + (m & 7)] =
              f2bf(acc[mi][ni][r]);
        }
  }
  __syncthreads();
  const int b_ = m0 >> 12;                    // batch index (tokens 4096/batch)
  const int rsub = lane >> 4, chk = lane & 15;
#pragma unroll
  for (int i = 0; i < 8; ++i) {
    const int rr = i * 16 + wave * 4 + rsub;  // Ep row (token, or chan for vT)
    bf16x8 v = *(const bf16x8*)(&Sh[rr * 128 + ((chk ^ (rr & 15)) * 8)]);
    if (mat == 2) {
      const int cg = (n0 + rr) & 511;
      const int h = cg >> 6, d = cg & 63;
      const int nb = (m0 & (kN - 1)) + chk * 8;
      *(bf16x8*)(vT + ((size_t)((b_ * kNH + h) * kHD + d)) * kN + nb) = v;
    } else {
      const int n_ = (m0 & (kN - 1)) + rr;
      const int cg = (n0 + chk * 8) & 511;
      if (mat == 3) {
        *(bf16x8*)(ci + ((size_t)(b_ * kN + n_)) * kC + cg) = v;
      } else {
        const int h = cg >> 6, d = cg & 63;
        short* dst = (mat == 0) ? q : k;
        *(bf16x8*)(dst + ((size_t)((b_ * kNH + h) * kN + n_)) * kHD + d) = v;
      }
    }
  }
}

// K2: depthwise conv, vectorized bf16x8 (uses dwkT + dwb from wb).
__global__ __launch_bounds__(256) void dwconv(
    const short* __restrict__ ci, const short* __restrict__ wb,
    short* __restrict__ cb) {
  const int e0 = (blockIdx.x * 256 + threadIdx.x) * 8;
  const int c0 = e0 & (kC - 1);
  const int bn = e0 >> 9;
  const int n_ = bn & (kN - 1);
  bf16x8 xc = ld8(ci + e0);
  bf16x8 xm, xp;
  if (n_ > 0) xm = ld8(ci + e0 - kC);
  else
#pragma unroll
    for (int i = 0; i < 8; ++i) xm[i] = 0;
  if (n_ < kN - 1) xp = ld8(ci + e0 + kC);
  else
#pragma unroll
    for (int i = 0; i < 8; ++i) xp[i] = 0;
  bf16x8 w0 = ld8(wb + kWAll + 2048 + c0);
  bf16x8 w1 = ld8(wb + kWAll + 2048 + 512 + c0);
  bf16x8 w2 = ld8(wb + kWAll + 2048 + 1024 + c0);
  bf16x8 bi = ld8(wb + kWAll + 1536 + c0);
  bf16x8 o;
#pragma unroll
  for (int i = 0; i < 8; ++i) {
    float a = bf2f(bi[i]) + bf2f(xm[i]) * bf2f(w0[i]) +
              bf2f(xc[i]) * bf2f(w1[i]) + bf2f(xp[i]) * bf2f(w2[i]);
    o[i] = f2bf(a);
  }
  *(bf16x8*)(cb + e0) = o;
}

// ---------------------------------------------------------------------------
// K3: flash attention v10 — v9 (64 q-rows/wave) + 2 kt per barrier.
//  - Quad-buffered LDS (K 64 KB + V 72 KB = 136 KB, 1 blk/CU as before):
//    barriers 32 -> 16; tile-b's QK MFMAs are independent of tile-a's
//    softmax/PV -> scheduler fills the exp2 chain stalls (R7 showed ~40%
//    of per-kt time is stall with no pipe >50%).
//  - K via gload_lds (XOR-source swizzle); V manual permuted staging.
//  - ks=1 partials combined into ks=0 via LDS overlay (68 KB, fits).
// ---------------------------------------------------------------------------
__global__ __launch_bounds__(512, 2) void attn_flash(
    const short* __restrict__ q, const short* __restrict__ k,
    const short* __restrict__ vT, short* __restrict__ attn) {
  __shared__ __align__(16) short SMEM[69632];          // 139264 B
  short* Kb = SMEM;                                    // [buf][tl][ks][64*64]
  short* Vb = SMEM + 32768;                            // [buf][tl][sv][64*72]
  const int t = threadIdx.x;
  const int wave = t >> 6;           // 0..7
  const int lane = t & 63;
  const int row = lane & 15;
  const int quad = lane >> 4;
  const int qg = wave & 3;           // q-group (64 rows each)
  const int ks = wave >> 2;          // key-stream (0: keys 0..2047, 1: rest)

  const int slot = blockIdx.x & 7;
  const int inner = blockIdx.x >> 3;          // 0..31
  const int bh = slot * 2 + (inner & 1);
  const int q0 = (inner >> 1) * 256 + qg * 64;

  const short* qbase = q + (size_t)(bh * kN + q0) * kHD;
  const short* kbase = k + (size_t)bh * kN * kHD;
  const short* vbase = vT + (size_t)bh * kHD * kN;

  bf16x8 qb[4][2];
#pragma unroll
  for (int g = 0; g < 4; ++g) {
    qb[g][0] = *(const bf16x8*)(qbase + (g * 16 + row) * kHD + quad * 8);
    qb[g][1] = *(const bf16x8*)(qbase + (g * 16 + row) * kHD + 32 + quad * 8);
  }

  const f32x4 z4 = {0.0f, 0.0f, 0.0f, 0.0f};   // persistent zero C-block

  f32x4 o[4][4];   // O^T partial accumulators (this wave's key half)
#pragma unroll
  for (int g = 0; g < 4; ++g)
#pragma unroll
    for (int j = 0; j < 4; ++j)
#pragma unroll
      for (int r = 0; r < 4; ++r) o[g][j][r] = 0.0f;
  float l_[4] = {0.0f, 0.0f, 0.0f, 0.0f};

  // K staging (gload_lds): XOR-source swizzle; stages BOTH kt of a pair for
  // BOTH streams (4 tiles). Dest linear, read side XORs back.
  const int ksrow = lane >> 3;
  const int kschunk = (lane & 7) ^ ksrow;
  auto stage_k = [&](int buf, int ktbase) {
#pragma unroll
    for (int tl = 0; tl < 2; ++tl)
#pragma unroll
      for (int s2 = 0; s2 < 2; ++s2)
        gload_lds16(
            kbase + (size_t)(s2 * 2048 + (ktbase + tl) * 64 + wave * 8 + ksrow) * 64 +
                kschunk * 8,
            &Kb[((buf * 2 + tl) * 2 + s2) * 4096 + wave * 512]);
  };

  // V staging: threads 0-255 stage stream-0 tiles, 256-511 stream-1 tiles.
  const int sv = t >> 8;
  const int ii = t & 255;
  const int i0 = ii, i1 = ii + 256;
  const int sr0 = i0 >> 3, sc0 = i0 & 7;
  const int sr1 = i1 >> 3, sc1 = i1 & 7;
  const int vb0 = (sc0 >> 2) * 32 + (sc0 & 1) * 16 + (sc0 & 2) * 2;
  const int vb1 = (sc1 >> 2) * 32 + (sc1 & 1) * 16 + (sc1 & 2) * 2;

  auto stage_v = [&](int buf, int tl, bf16x8 v0, bf16x8 v1) {
    short* base = &Vb[((buf * 2 + tl) * 2 + sv) * 4608];
    *(short4*)(&base[sr0 * 72 + vb0]) = make_short4(v0[0], v0[1], v0[2], v0[3]);
    *(short4*)(&base[sr0 * 72 + vb0 + 8]) = make_short4(v0[4], v0[5], v0[6], v0[7]);
    *(short4*)(&base[sr1 * 72 + vb1]) = make_short4(v1[0], v1[1], v1[2], v1[3]);
    *(short4*)(&base[sr1 * 72 + vb1 + 8]) = make_short4(v1[4], v1[5], v1[6], v1[7]);
  };

  // fragment-read chunk offsets (constant per lane)
  const int c0s = ((quad) ^ (row & 7)) * 8;
  const int c1s = ((quad + 4) ^ (row & 7)) * 8;

  // per-tile compute: QK -> softmax -> PV (4 q-groups)
  auto tile_step = [&](const short* kt_base, const short* vt_base) {
    f32x4 s[4][4];
    __builtin_amdgcn_s_setprio(1);
#pragma unroll
    for (int jk = 0; jk < 4; ++jk) {
      const short* kr = kt_base + (jk * 16 + row) * 64;
      bf16x8 a0 = *(const bf16x8*)(kr + c0s);
      bf16x8 a1 = *(const bf16x8*)(kr + c1s);
#pragma unroll
      for (int g = 0; g < 4; ++g) {
        s[g][jk] = __builtin_amdgcn_mfma_f32_16x16x32_bf16(a0, qb[g][0], z4, 0, 0, 0);
        s[g][jk] = __builtin_amdgcn_mfma_f32_16x16x32_bf16(a1, qb[g][1], s[g][jk], 0, 0, 0);
      }
    }
    __builtin_amdgcn_s_setprio(0);

    bf16x8 pb[4][2];
#pragma unroll
    for (int g = 0; g < 4; ++g) {
      float tj[4];
#pragma unroll
      for (int jk = 0; jk < 4; ++jk) {
#pragma unroll
        for (int r = 0; r < 4; ++r) s[g][jk][r] = exp2_(s[g][jk][r]);
        tj[jk] = (s[g][jk][0] + s[g][jk][1]) + (s[g][jk][2] + s[g][jk][3]);
      }
      l_[g] += (tj[0] + tj[1]) + (tj[2] + tj[3]);
#pragma unroll
      for (int c = 0; c < 2; ++c) {
        union { unsigned u[4]; bf16x8 v; } pu;
        pu.u[0] = pk2bf(s[g][2 * c][0], s[g][2 * c][1]);
        pu.u[1] = pk2bf(s[g][2 * c][2], s[g][2 * c][3]);
        pu.u[2] = pk2bf(s[g][2 * c + 1][0], s[g][2 * c + 1][1]);
        pu.u[3] = pk2bf(s[g][2 * c + 1][2], s[g][2 * c + 1][3]);
        pb[g][c] = pu.v;
      }
    }

    __builtin_amdgcn_s_setprio(1);
#pragma unroll
    for (int jd = 0; jd < 4; ++jd) {
      const short* vb = vt_base + (jd * 16 + row) * 72 + quad * 8;
#pragma unroll
      for (int c = 0; c < 2; ++c) {
        bf16x8 av = *(const bf16x8*)(vb + c * 32);
#pragma unroll
        for (int g = 0; g < 4; ++g)
          o[g][jd] = __builtin_amdgcn_mfma_f32_16x16x32_bf16(
              av, pb[g][c], o[g][jd], 0, 0, 0);
      }
    }
    __builtin_amdgcn_s_setprio(0);
  };

  { // prologue: pair 0 (kt 0,1) of both streams -> buffer 0
    stage_k(0, 0);
#pragma unroll
    for (int tl = 0; tl < 2; ++tl) {
      bf16x8 a = *(const bf16x8*)(vbase + (size_t)sr0 * kN + sv * 2048 + tl * 64 + sc0 * 8);
      bf16x8 b = *(const bf16x8*)(vbase + (size_t)sr1 * kN + sv * 2048 + tl * 64 + sc1 * 8);
      stage_v(0, tl, a, b);
    }
  }
  __syncthreads();

  for (int p = 0; p < 16; ++p) {
    const int cur = p & 1;
    const bool more = (p < 15);
    bf16x8 vn00, vn01, vn10, vn11;
    if (more) {
      stage_k(1 - cur, 2 * p + 2);
      const int off = sv * 2048 + (2 * p + 2) * 64;
      vn00 = *(const bf16x8*)(vbase + (size_t)sr0 * kN + off + sc0 * 8);
      vn01 = *(const bf16x8*)(vbase + (size_t)sr1 * kN + off + sc1 * 8);
      vn10 = *(const bf16x8*)(vbase + (size_t)sr0 * kN + off + 64 + sc0 * 8);
      vn11 = *(const bf16x8*)(vbase + (size_t)sr1 * kN + off + 64 + sc1 * 8);
    }

    tile_step(&Kb[((cur * 2 + 0) * 2 + ks) * 4096], &Vb[((cur * 2 + 0) * 2 + ks) * 4608]);

    if (more) {
      stage_v(1 - cur, 0, vn00, vn01);
      stage_v(1 - cur, 1, vn10, vn11);
    }

    tile_step(&Kb[((cur * 2 + 1) * 2 + ks) * 4096], &Vb[((cur * 2 + 1) * 2 + ks) * 4608]);
    __syncthreads();
  }

  // ---- combine key-halves via LDS overlay (barrier-protected), finalize ----
  float* Of = (float*)SMEM;            // 64 slots x 256 floats = 64 KB
  float* Lf = (float*)SMEM + 16384;    // 4 slots x 256 floats = 4 KB
  if (ks == 1) {
#pragma unroll
    for (int g = 0; g < 4; ++g) {
#pragma unroll
      for (int jd = 0; jd < 4; ++jd)
#pragma unroll
        for (int r = 0; r < 4; ++r)
          Of[(g * 16 + jd * 4 + r) * 256 + qg * 64 + lane] = o[g][jd][r];
      Lf[g * 256 + qg * 64 + lane] = l_[g];
    }
  }
  __syncthreads();
  if (ks == 0) {
#pragma unroll
    for (int g = 0; g < 4; ++g) {
#pragma unroll
      for (int jd = 0; jd < 4; ++jd)
#pragma unroll
        for (int r = 0; r < 4; ++r)
          o[g][jd][r] += Of[(g * 16 + jd * 4 + r) * 256 + qg * 64 + lane];
      l_[g] += Lf[g * 256 + qg * 64 + lane];
    }
    const int b_ = bh >> 3, h = bh & 7;
#pragma unroll
    for (int g = 0; g < 4; ++g) {
      float lt = l_[g];
      lt += __shfl_xor(lt, 16);
      lt += __shfl_xor(lt, 32);
      const float linv = 1.0f / lt;
      const int n_ = q0 + g * 16 + row;
      short* ob = attn + (size_t)(b_ * kN + n_) * kC + h * kHD + quad * 4;
#pragma unroll
      for (int jd = 0; jd < 4; ++jd) {
        short4 st = make_short4(f2bf(o[g][jd][0] * linv), f2bf(o[g][jd][1] * linv),
                                f2bf(o[g][jd][2] * linv), f2bf(o[g][jd][3] * linv));
        *(short4*)(ob + jd * 16) = st;
      }
    }
  }
}

// ---------------------------------------------------------------------------
// K4: out = [attn|cb] @ [Wa|Wo]^T, GEMM M=8192 N=512 K=1024 (K-concat),
// BK=64, XOR-source-swizzled staging. LDS-bounce epilogue. NEW: XCD-aware
// bijective blockIdx swizzle (nwg=512, %8==0).
// ---------------------------------------------------------------------------
template <typename TO>
__device__ __forceinline__ void out_body(
    const short* __restrict__ attn, const short* __restrict__ cb,
    const short* __restrict__ wb, TO* __restrict__ out) {
  __shared__ __align__(16) short Sh[16384];     // 32 KB: As | Bs | epilogue
  short* As = Sh;                               // 128*64
  short* Bs = Sh + 8192;                        // 64*64
  const int t = threadIdx.x;
  const int wave = t >> 6, lane = t & 63;
  const int row = lane & 15, quad = lane >> 4;
  const int swz = (blockIdx.x & 7) * 64 + (blockIdx.x >> 3);    // XCD swizzle
  const int bn = swz & 7;
  const int bm = swz >> 3;
  const int m0 = bm * 128, n0 = bn * 64;
  const int wm = wave & 1, wn = wave >> 1;
  const int lrow = lane >> 3, lch = lane & 7;

  f32x4 acc[4][2];
#pragma unroll
  for (int mi = 0; mi < 4; ++mi)
#pragma unroll
    for (int ni = 0; ni < 2; ++ni)
#pragma unroll
      for (int r = 0; r < 4; ++r) acc[mi][ni][r] = 0.0f;

  const short* Wa = wb + 4 * kWElems;
  const short* Wo = wb + 5 * kWElems;

  for (int k0 = 0; k0 < 1024; k0 += 64) {
    const short* Asrc = (k0 < 512) ? attn : cb;
    const short* Bsrc = (k0 < 512) ? Wa : Wo;
    const int ka = k0 & 511;
#pragma unroll
    for (int p = 0; p < 4; ++p) {
      const int m = wave * 32 + p * 8 + lrow;
      const int kch = lch ^ (m & 7);
      gload_lds16(Asrc + (size_t)(m0 + m) * kC + ka + kch * 8,
                  &As[(wave * 32 + p * 8) * 64]);
    }
#pragma unroll
    for (int p = 0; p < 2; ++p) {
      const int n = wave * 16 + p * 8 + lrow;
      const int kch = lch ^ (n & 7);
      gload_lds16(Bsrc + (size_t)(n0 + n) * kC + ka + kch * 8,
                  &Bs[(wave * 16 + p * 8) * 64]);
    }
    __syncthreads();

#pragma unroll
    for (int kk2 = 0; kk2 < 2; ++kk2) {
      bf16x8 af[4], bfr[2];
#pragma unroll
      for (int mi = 0; mi < 4; ++mi) {
        const int m = wm * 64 + mi * 16 + row;
        const int ch = (kk2 * 4 + quad) ^ (m & 7);
        af[mi] = *(const bf16x8*)(&As[m * 64 + ch * 8]);
      }
#pragma unroll
      for (int ni = 0; ni < 2; ++ni) {
        const int n = wn * 32 + ni * 16 + row;
        const int ch = (kk2 * 4 + quad) ^ (n & 7);
        bfr[ni] = *(const bf16x8*)(&Bs[n * 64 + ch * 8]);
      }
#pragma unroll
      for (int mi = 0; mi < 4; ++mi)
#pragma unroll
        for (int ni = 0; ni < 2; ++ni)
          acc[mi][ni] = __builtin_amdgcn_mfma_f32_16x16x32_bf16(
              af[mi], bfr[ni], acc[mi][ni], 0, 0, 0);
    }
    __syncthreads();
  }

  // ---- epilogue: LDS bounce -> coalesced 16B stores ----
  if constexpr (sizeof(TO) == 4) {
    float* Shf = (float*)Sh;   // 128 x 64 f32 = 32 KB (exact)
#pragma unroll
    for (int mi = 0; mi < 4; ++mi)
#pragma unroll
      for (int ni = 0; ni < 2; ++ni)
#pragma unroll
        for (int r = 0; r < 4; ++r) {
          const int m = wm * 64 + mi * 16 + quad * 4 + r;
          const int n = wn * 32 + ni * 16 + row;
          Shf[m * 64 + (((n >> 2) ^ (m & 15)) * 4) + (n & 3)] = acc[mi][ni][r];
        }
    __syncthreads();
    const int rsub = lane >> 4, chk = lane & 15;
#pragma unroll
    for (int i = 0; i < 8; ++i) {
      const int rr = i * 16 + wave * 4 + rsub;
      float4 v = *(const float4*)(&Shf[rr * 64 + ((chk ^ (rr & 15)) * 4)]);
      *(float4*)((float*)out + (size_t)(m0 + rr) * kC + n0 + chk * 4) = v;
    }
  } else {
#pragma unroll
    for (int mi = 0; mi < 4; ++mi)
#pragma unroll
      for (int ni = 0; ni < 2; ++ni)
#pragma unroll
        for (int r = 0; r < 4; ++r) {
          const int m = wm * 64 + mi * 16 + quad * 4 + r;
          const int n = wn * 32 + ni * 16 + row;
          Sh[m * 64 + (((n >> 3) ^ (m & 7)) * 8) + (n & 7)] =
              f2bf(acc[mi][ni][r]);
        }
    __syncthreads();
    const int rsub = lane >> 3, chk = lane & 7;
#pragma unroll
    for (int i = 0; i < 4; ++i) {
      const int rr = i * 32 + wave * 8 + rsub;
      bf16x8 v = *(const bf16x8*)(&Sh[rr * 64 + ((chk ^ (rr & 7)) * 8)]);
      *(bf16x8*)((short*)out + (size_t)(m0 + rr) * kC + n0 + chk * 8) = v;
    }
  }
}

__global__ __launch_bounds__(256, 4) void out_gemm(
    const short* __restrict__ attn, const short* __restrict__ cb,
    const short* __restrict__ wb, const int* __restrict__ flag, void* out) {
  if (*flag)
    out_body<short>(attn, cb, wb, (short*)out);
  else
    out_body<float>(attn, cb, wb, (float*)out);
}

extern "C" void kernel_launch(void* const* d_in, const int* in_sizes, int n_in,
                              void* d_out, int out_size, void* d_ws, size_t ws_size,
                              hipStream_t stream) {
  const void* x   = d_in[0];
  const void* Wq  = d_in[1];
  const void* Wk  = d_in[2];
  const void* Wv  = d_in[3];
  const void* Wa  = d_in[4];
  const void* Wc  = d_in[5];
  const void* dwk = d_in[6];
  const void* dwb = d_in[7];
  const void* Wco = d_in[8];

  short* ws = (short*)d_ws;
  const size_t E = (size_t)kBN * kC;
  int*   flag = (int*)ws;
  short* wb   = ws + 256;
  short* q    = wb + kWAll + kWExtra;
  short* k    = q + E;
  short* vT   = k + E;
  short* ci   = vT + E;
  short* cb   = ci + E;
  short* attn = ci;   // attn overwrites ci (consumed by dwconv first)
  short* xb   = cb;   // consumed by proj_gemm before dwconv writes cb

  detect_dtype<<<1, 64, 0, stream>>>((const unsigned*)x, flag);
  const int cvt_threads = kW8 + kWExtra + kX8;
  convert_all<<<(cvt_threads + 255) / 256, 256, 0, stream>>>(
      Wq, Wk, Wv, Wc, Wa, Wco, dwk, dwb, x, flag, wb, xb);
  proj_gemm<<<1024, 256, 0, stream>>>(xb, wb, q, k, vT, ci);
  dwconv<<<(kBN * kC) / (256 * 8), 256, 0, stream>>>(ci, wb, cb);
  attn_flash<<<256, 512, 0, stream>>>(q, k, vT, attn);
  out_gemm<<<512, 256, 0, stream>>>(attn, cb, wb, flag, d_out);
}